// Round 4
// baseline (90.568 us; speedup 1.0000x reference)
//
#include <hip/hip_runtime.h>

typedef float f32x4 __attribute__((ext_vector_type(4)));
typedef short s16x8 __attribute__((ext_vector_type(8)));

#define M_DIM 32
#define N_DIM 8192
#define K_DIM 8192
#define NBLK (K_DIM / 16)     // 512 fp4 blocks along K
#define KSTEPS 32             // k-steps per block (1024 k / 32)
#define DEPTH 2               // W-staging ring depth
#define OPS 5                 // vmem ops per staged step
#define SLOT_BYTES 4352       // Wg0_lo 1K | Wg0_hi 1K | Wg1_lo 1K | Wg1_hi 1K | SC 256
#define WAVE_LDS (DEPTH * SLOT_BYTES)   // 8704 B per wave
#define XQ_BYTES 65536        // persistent xpack K-slice (32 ksteps * 2KB)

// float -> bf16 bits, round-to-nearest-even (data has no NaNs)
__device__ inline unsigned short f2bf(float f) {
    unsigned int u = __float_as_uint(f);
    u = (u + 0x7FFFu + ((u >> 16) & 1u)) >> 16;
    return (unsigned short)u;
}

// Nearest FP4 (e2m1); ties at the boundary go DOWN (searchsorted side='left').
__device__ inline float round_fp4(float x) {
    float a = fabsf(x);
    float g;
    if (a > 2.5f)        g = (a > 5.0f) ? 6.0f : ((a > 3.5f) ? 4.0f : 3.0f);
    else if (a > 1.25f)  g = (a > 1.75f) ? 2.0f : 1.5f;
    else                 g = (a > 0.75f) ? 1.0f : ((a > 0.25f) ? 0.5f : 0.0f);
    return copysignf(g, x);
}

// Saturating RNE cast to float8_e4m3fn and back (v >= 0 here).
__device__ inline float cast_e4m3(float v) {
    v = fminf(v, 448.0f);
    if (v < 0.015625f) {                       // subnormal range, step 2^-9
        return rintf(v * 512.0f) * (1.0f / 512.0f);
    }
    int e; float m = frexpf(v, &e);            // m in [0.5, 1)
    return ldexpf(rintf(m * 16.0f) * 0.0625f, e);
}

// global_load_lds: LDS dest is WAVE-UNIFORM base; HW writes base + lane*size.
__device__ __forceinline__ void async_copy16(const void* g, void* l) {
    __builtin_amdgcn_global_load_lds((const __attribute__((address_space(1))) void*)g,
                                     (__attribute__((address_space(3))) void*)l, 16, 0, 0);
}
__device__ __forceinline__ void async_copy4(const void* g, void* l) {
    __builtin_amdgcn_global_load_lds((const __attribute__((address_space(1))) void*)g,
                                     (__attribute__((address_space(3))) void*)l, 4, 0, 0);
}

template <int VM>
__device__ __forceinline__ void waitvm() {
    asm volatile("s_waitcnt vmcnt(%0)" :: "i"(VM) : "memory");
}
__device__ __forceinline__ void wait_lds_reads_done() {
    asm volatile("s_waitcnt lgkmcnt(0)" ::: "memory");
}

// ---------------------------------------------------------------------------
// out[m][n] = bias[n]  (runs every call; gemm atomics accumulate onto it)
// ---------------------------------------------------------------------------
__global__ void init_out(const float* __restrict__ bias, float* __restrict__ out) {
    int i = blockIdx.x * blockDim.x + threadIdx.x;   // 65536 threads, 4 floats each
    f32x4 b = *(const f32x4*)(bias + ((i * 4) & (N_DIM - 1)));
    *(f32x4*)(out + (size_t)i * 4) = b;
}

// ---------------------------------------------------------------------------
// Phase 1: NVFP4 fake-quant of x, packed into MFMA B-fragment layout (bf16).
// Short index: kstep*1024 + t*512 + lane*8 + j  holds
//   x_dq[m = t*16 + (lane&15)][k = kstep*32 + (lane>>4)*8 + j]
// (t-sections separated so gemm's b0/b1 ds_read_b128 are stride-16B, conflict-free)
// ---------------------------------------------------------------------------
__global__ void quant_pack_x(const float* __restrict__ x,
                             const float* __restrict__ input_scale,
                             unsigned short* __restrict__ xpack) {
    int tid = blockIdx.x * blockDim.x + threadIdx.x;   // 16384 threads
    int m = tid >> 9;          // row 0..31
    int b = tid & 511;         // 16-block along K
    const float is = input_scale[0];

    const float* xp = x + (size_t)m * K_DIM + b * 16;
    f32x4 l0 = *(const f32x4*)(xp);
    f32x4 l1 = *(const f32x4*)(xp + 4);
    f32x4 l2 = *(const f32x4*)(xp + 8);
    f32x4 l3 = *(const f32x4*)(xp + 12);
    float v[16];
    #pragma unroll
    for (int i = 0; i < 4; ++i) { v[i]=l0[i]; v[4+i]=l1[i]; v[8+i]=l2[i]; v[12+i]=l3[i]; }

    float amax = 0.f;
    #pragma unroll
    for (int i = 0; i < 16; ++i) amax = fmaxf(amax, fabsf(v[i]));

    float sf = cast_e4m3(amax / 6.0f / is);
    float scale = sf * is;

    int kstep = b >> 1;
    int t = m >> 4;
    int mrow = m & 15;
    unsigned short* base = xpack + (size_t)kstep * 1024 + t * 512;
    #pragma unroll
    for (int i = 0; i < 16; ++i) {
        float q = 0.f;
        if (scale > 0.f) q = round_fp4(v[i] / scale) * scale;
        int g = ((b & 1) << 1) + (i >> 3);   // k-group 0..3 within kstep
        int lane = g * 16 + mrow;
        int j = i & 7;
        base[lane * 8 + j] = f2bf(q);
    }
}

// ---------------------------------------------------------------------------
// Phase 2: split-K GEMM. Grid = (32 n-tiles) x (8 k-splits) = 256 blocks,
// 1 block/CU. Block: 256 N-rows, 1024 K. xpack K-slice (64KB) loaded into
// LDS ONCE and shared by all 8 waves (each wave owns 32 rows, same K-range).
// W + wscale staged via DEPTH=2 counted-vmcnt ring. Partials atomicAdd'd
// into bias-initialized out.
// ---------------------------------------------------------------------------
__global__ __launch_bounds__(512, 2) void gemm_kernel(
    const float* __restrict__ W,
    const float* __restrict__ wscale,
    const float* __restrict__ ws2p,
    const unsigned short* __restrict__ xpack,
    float* __restrict__ out)
{
    __shared__ __align__(16) unsigned char lds[XQ_BYTES + 8 * WAVE_LDS];  // 135168 B
    unsigned char* xq   = lds;             // persistent x slice
    unsigned char* ring = lds + XQ_BYTES;

    const int wave = threadIdx.x >> 6;
    const int lane = threadIdx.x & 63;
    const int lrow = lane & 15;   // W-row (n) sub-index / x m-col
    const int lgrp = lane >> 4;   // k-group 0..3
    const int nb = blockIdx.x;    // 0..31
    const int kb = blockIdx.y;    // 0..7
    const int rbase = nb * 256 + wave * 32;
    const float ws2 = ws2p[0];

    // ---- cooperative load of xpack K-slice (64KB) into LDS ----
    {
        const unsigned short* src = xpack + (size_t)kb * 32768;  // 32 ksteps * 1024 shorts
        #pragma unroll
        for (int p = 0; p < 8; ++p) {
            int c = wave * 8 + p;                         // 1KB chunk 0..63
            async_copy16(src + (size_t)c * 512 + lane * 8, xq + c * 1024);
        }
    }
    waitvm<0>();
    __syncthreads();

    // ---- per-lane global sources for the W/scale ring ----
    const float* wsrc0 = W + (size_t)(rbase + lrow) * K_DIM + kb * 1024 + lgrp * 8;
    const float* wsrc1 = wsrc0 + (size_t)16 * K_DIM;
    // scale staging: lane l holds scale for (rg=l>>5, row16=(l>>1)&15, kbh=l&1)
    const float* ssrc = wscale
        + (size_t)(rbase + (lane >> 5) * 16 + ((lane >> 1) & 15)) * NBLK
        + kb * 64 + (lane & 1);

    unsigned char* wb = ring + wave * WAVE_LDS;

    f32x4 acc00 = {0,0,0,0}, acc01 = {0,0,0,0};
    f32x4 acc10 = {0,0,0,0}, acc11 = {0,0,0,0};

    auto stage = [&](int s) {
        unsigned char* sb = wb + (s & (DEPTH - 1)) * SLOT_BYTES;
        const float* wp0 = wsrc0 + s * 32;
        const float* wp1 = wsrc1 + s * 32;
        async_copy16(wp0,     sb);
        async_copy16(wp0 + 4, sb + 1024);
        async_copy16(wp1,     sb + 2048);
        async_copy16(wp1 + 4, sb + 3072);
        async_copy4(ssrc + 2 * s, sb + 4096);
    };

    const int scoff = ((lrow << 1) | (lgrp >> 1)) << 2;

    auto step = [&](int s, bool do_stage) {
        const unsigned char* sb = wb + (s & (DEPTH - 1)) * SLOT_BYTES;
        f32x4 a0 = *(const f32x4*)(sb +    0 + lane * 16);
        f32x4 a1 = *(const f32x4*)(sb + 1024 + lane * 16);
        f32x4 a2 = *(const f32x4*)(sb + 2048 + lane * 16);
        f32x4 a3 = *(const f32x4*)(sb + 3072 + lane * 16);
        float sc0 = *(const float*)(sb + 4096 + scoff);
        float sc1 = *(const float*)(sb + 4096 + 128 + scoff);
        const unsigned char* xb = xq + (size_t)s * 2048;
        s16x8 b0 = *(const s16x8*)(xb +        lane * 16);
        s16x8 b1 = *(const s16x8*)(xb + 1024 + lane * 16);
        wait_lds_reads_done();           // ring reads retired -> safe to overwrite
        if (do_stage) stage(s + DEPTH);
        sc0 *= ws2; sc1 *= ws2;
        s16x8 af0, af1;
        #pragma unroll
        for (int j = 0; j < 4; ++j) {
            af0[j]     = (short)f2bf(a0[j] * sc0);
            af0[4 + j] = (short)f2bf(a1[j] * sc0);
            af1[j]     = (short)f2bf(a2[j] * sc1);
            af1[4 + j] = (short)f2bf(a3[j] * sc1);
        }
        acc00 = __builtin_amdgcn_mfma_f32_16x16x32_bf16(af0, b0, acc00, 0, 0, 0);
        acc01 = __builtin_amdgcn_mfma_f32_16x16x32_bf16(af0, b1, acc01, 0, 0, 0);
        acc10 = __builtin_amdgcn_mfma_f32_16x16x32_bf16(af1, b0, acc10, 0, 0, 0);
        acc11 = __builtin_amdgcn_mfma_f32_16x16x32_bf16(af1, b1, acc11, 0, 0, 0);
    };

    // prologue: fill the ring
    stage(0);
    stage(1);

    // steady state: entry outstanding = 10, release slot s at vmcnt(5)
    #pragma unroll 2
    for (int s = 0; s < KSTEPS - DEPTH; ++s) {
        waitvm<OPS>();
        step(s, true);
    }
    waitvm<OPS>(); step(KSTEPS - 2, false);
    waitvm<0>();   step(KSTEPS - 1, false);

    // ---- epilogue: atomic accumulate (C/D: col=lane&15, row=(lane>>4)*4+r) ----
    const int nr = (lane >> 4) * 4;
    #pragma unroll
    for (int r = 0; r < 4; ++r) {
        atomicAdd(out + (size_t)(lrow)      * N_DIM + rbase +      nr + r, acc00[r]);
        atomicAdd(out + (size_t)(16 + lrow) * N_DIM + rbase +      nr + r, acc01[r]);
        atomicAdd(out + (size_t)(lrow)      * N_DIM + rbase + 16 + nr + r, acc10[r]);
        atomicAdd(out + (size_t)(16 + lrow) * N_DIM + rbase + 16 + nr + r, acc11[r]);
    }
}

extern "C" void kernel_launch(void* const* d_in, const int* in_sizes, int n_in,
                              void* d_out, int out_size, void* d_ws, size_t ws_size,
                              hipStream_t stream) {
    const float* x           = (const float*)d_in[0];
    const float* weight_fp4  = (const float*)d_in[1];
    const float* bias        = (const float*)d_in[2];
    const float* input_scale = (const float*)d_in[3];
    const float* wscale      = (const float*)d_in[4];
    const float* ws2         = (const float*)d_in[5];
    float* out = (float*)d_out;
    unsigned short* xpack = (unsigned short*)d_ws;   // 512 KB

    init_out<<<256, 256, 0, stream>>>(bias, out);
    quant_pack_x<<<64, 256, 0, stream>>>(x, input_scale, xpack);
    gemm_kernel<<<dim3(32, 8), 512, 0, stream>>>(weight_fp4, wscale, ws2, xpack, out);
}

// Round 5
// 73.722 us; speedup vs baseline: 1.2285x; 1.2285x over previous
//
#include <hip/hip_runtime.h>

typedef float f32x4 __attribute__((ext_vector_type(4)));
typedef short s16x8 __attribute__((ext_vector_type(8)));

#define M_DIM 32
#define N_DIM 8192
#define K_DIM 8192
#define NBLK (K_DIM / 16)   // 512 fp4 blocks along K
#define KSPLIT 4
#define WSTEPS 16           // MFMA k-steps per wave (512 k / 32)
#define SCL_LD 129          // padded LDS stride for scales

// float -> bf16 bits, round-to-nearest-even (data has no NaNs)
__device__ inline unsigned short f2bf(float f) {
    unsigned int u = __float_as_uint(f);
    u = (u + 0x7FFFu + ((u >> 16) & 1u)) >> 16;
    return (unsigned short)u;
}

// Nearest FP4 (e2m1); ties at the boundary go DOWN (searchsorted side='left').
__device__ inline float round_fp4(float x) {
    float a = fabsf(x);
    float g;
    if (a > 2.5f)        g = (a > 5.0f) ? 6.0f : ((a > 3.5f) ? 4.0f : 3.0f);
    else if (a > 1.25f)  g = (a > 1.75f) ? 2.0f : 1.5f;
    else                 g = (a > 0.75f) ? 1.0f : ((a > 0.25f) ? 0.5f : 0.0f);
    return copysignf(g, x);
}

// Saturating RNE cast to float8_e4m3fn and back (v >= 0 here).
__device__ inline float cast_e4m3(float v) {
    v = fminf(v, 448.0f);
    if (v < 0.015625f) {                       // subnormal range, step 2^-9
        return rintf(v * 512.0f) * (1.0f / 512.0f);
    }
    int e; float m = frexpf(v, &e);            // m in [0.5, 1)
    return ldexpf(rintf(m * 16.0f) * 0.0625f, e);
}

// ---------------------------------------------------------------------------
// out[m][n] = bias[n]  (runs every call; gemm atomics accumulate onto it)
// ---------------------------------------------------------------------------
__global__ void init_out(const float* __restrict__ bias, float* __restrict__ out) {
    int i = blockIdx.x * blockDim.x + threadIdx.x;   // 65536 threads, 4 floats each
    f32x4 b = *(const f32x4*)(bias + ((i * 4) & (N_DIM - 1)));
    *(f32x4*)(out + (size_t)i * 4) = b;
}

// ---------------------------------------------------------------------------
// Phase 1: NVFP4 fake-quant of x, packed into MFMA B-fragment layout (bf16).
// Short index: kstep*1024 + t*512 + lane*8 + j  holds
//   x_dq[m = t*16 + (lane&15)][k = kstep*32 + (lane>>4)*8 + j]
// ---------------------------------------------------------------------------
__global__ void quant_pack_x(const float* __restrict__ x,
                             const float* __restrict__ input_scale,
                             unsigned short* __restrict__ xpack) {
    int tid = blockIdx.x * blockDim.x + threadIdx.x;   // 16384 threads
    int m = tid >> 9;          // row 0..31
    int b = tid & 511;         // 16-block along K
    const float is = input_scale[0];

    const float* xp = x + (size_t)m * K_DIM + b * 16;
    f32x4 l0 = *(const f32x4*)(xp);
    f32x4 l1 = *(const f32x4*)(xp + 4);
    f32x4 l2 = *(const f32x4*)(xp + 8);
    f32x4 l3 = *(const f32x4*)(xp + 12);
    float v[16];
    #pragma unroll
    for (int i = 0; i < 4; ++i) { v[i]=l0[i]; v[4+i]=l1[i]; v[8+i]=l2[i]; v[12+i]=l3[i]; }

    float amax = 0.f;
    #pragma unroll
    for (int i = 0; i < 16; ++i) amax = fmaxf(amax, fabsf(v[i]));

    float sf = cast_e4m3(amax / 6.0f / is);
    float scale = sf * is;

    int kstep = b >> 1;
    int t = m >> 4;
    int mrow = m & 15;
    unsigned short* base = xpack + (size_t)kstep * 1024 + t * 512;
    #pragma unroll
    for (int i = 0; i < 16; ++i) {
        float q = 0.f;
        if (scale > 0.f) q = round_fp4(v[i] / scale) * scale;
        int g = ((b & 1) << 1) + (i >> 3);   // k-group 0..3 within kstep
        int lane = g * 16 + mrow;
        int j = i & 7;
        base[lane * 8 + j] = f2bf(q);
    }
}

// ---------------------------------------------------------------------------
// Phase 2: streaming split-K GEMM, shaped like a max-BW copy kernel.
// Grid = (512 n-tiles) x (4 k-splits), 256 threads (4 waves) per block
// -> 8 blocks/CU, 32 waves/CU (full residency, 8192 waves total).
// Each wave: 16 rows x 512 k, depth-2 VGPR software pipeline, W + xpack
// straight from global (xpack is L2-resident). Scales preloaded to LDS.
// Epilogue: intra-block LDS reduce (4 waves), then atomicAdd into
// bias-initialized out.
// ---------------------------------------------------------------------------
__global__ __launch_bounds__(256, 8) void gemm_kernel(
    const float* __restrict__ W,
    const float* __restrict__ wscale,
    const float* __restrict__ ws2p,
    const unsigned short* __restrict__ xpack,
    float* __restrict__ out)
{
    __shared__ float shm[16 * SCL_LD];   // 8256 B; scales, then reduce buffer

    const int wave = threadIdx.x >> 6;   // 0..3 : k sub-split within block
    const int lane = threadIdx.x & 63;
    const int lrow = lane & 15;          // W row (n) sub-index
    const int lgrp = lane >> 4;          // k-group 0..3
    const int n0 = blockIdx.x * 16;
    const int kb = blockIdx.y;           // 0..3
    const float ws2 = ws2p[0];

    // ---- preload scales * ws2: rows n0..n0+15, scale-cols kb*128..+128 ----
    {
        int t = threadIdx.x;
        int row = t >> 4;
        int c0 = (t & 15) * 8;
        const float* s = wscale + (size_t)(n0 + row) * NBLK + kb * 128 + c0;
        #pragma unroll
        for (int j = 0; j < 8; ++j)
            shm[row * SCL_LD + c0 + j] = s[j] * ws2;
    }
    __syncthreads();

    const int kofs = kb * 2048 + wave * 512;          // this wave's k start
    const float* wcur = W + (size_t)(n0 + lrow) * K_DIM + kofs + lgrp * 8;
    const unsigned short* xcur = xpack + (size_t)(kofs >> 5) * 1024 + lane * 8;
    const float* sbase = shm + lrow * SCL_LD + wave * 32 + (lgrp >> 1);

    f32x4 acc0 = {0,0,0,0}, acc1 = {0,0,0,0};

    // depth-2 software pipeline (compiler inserts the vmcnt waits)
    f32x4 a0 = *(const f32x4*)(wcur);
    f32x4 a1 = *(const f32x4*)(wcur + 4);
    s16x8 b0 = *(const s16x8*)(xcur);
    s16x8 b1 = *(const s16x8*)(xcur + 512);

    #pragma unroll
    for (int s = 0; s < WSTEPS; ++s) {
        f32x4 na0, na1; s16x8 nb0, nb1;
        if (s + 1 < WSTEPS) {             // static with full unroll
            na0 = *(const f32x4*)(wcur + 32);
            na1 = *(const f32x4*)(wcur + 36);
            nb0 = *(const s16x8*)(xcur + 1024);
            nb1 = *(const s16x8*)(xcur + 1536);
        }
        float sc = sbase[s * 2];
        s16x8 af;
        #pragma unroll
        for (int j = 0; j < 4; ++j) {
            af[j]     = (short)f2bf(a0[j] * sc);
            af[4 + j] = (short)f2bf(a1[j] * sc);
        }
        acc0 = __builtin_amdgcn_mfma_f32_16x16x32_bf16(af, b0, acc0, 0, 0, 0);
        acc1 = __builtin_amdgcn_mfma_f32_16x16x32_bf16(af, b1, acc1, 0, 0, 0);
        a0 = na0; a1 = na1; b0 = nb0; b1 = nb1;
        wcur += 32;
        xcur += 1024;
    }

    // ---- intra-block reduce over the 4 k-split waves ----
    __syncthreads();                      // scale reads done; reuse shm
    float* red = shm;                     // [4][512]
    #pragma unroll
    for (int r = 0; r < 4; ++r) {
        red[wave * 512 + lane * 8 + r]     = acc0[r];
        red[wave * 512 + lane * 8 + 4 + r] = acc1[r];
    }
    __syncthreads();

    // 256 threads -> 512 outputs; D layout: col(lane&15)=m, row((lane>>4)*4+r)=n
    #pragma unroll
    for (int h = 0; h < 2; ++h) {
        int j = threadIdx.x + h * 256;
        float v = red[j] + red[512 + j] + red[1024 + j] + red[1536 + j];
        int l = j >> 3, t = (j >> 2) & 1, r = j & 3;
        int m = t * 16 + (l & 15);
        int n = n0 + ((l >> 4) << 2) + r;
        atomicAdd(out + (size_t)m * N_DIM + n, v);
    }
}

extern "C" void kernel_launch(void* const* d_in, const int* in_sizes, int n_in,
                              void* d_out, int out_size, void* d_ws, size_t ws_size,
                              hipStream_t stream) {
    const float* x           = (const float*)d_in[0];
    const float* weight_fp4  = (const float*)d_in[1];
    const float* bias        = (const float*)d_in[2];
    const float* input_scale = (const float*)d_in[3];
    const float* wscale      = (const float*)d_in[4];
    const float* ws2         = (const float*)d_in[5];
    float* out = (float*)d_out;
    unsigned short* xpack = (unsigned short*)d_ws;   // 512 KB

    init_out<<<256, 256, 0, stream>>>(bias, out);
    quant_pack_x<<<64, 256, 0, stream>>>(x, input_scale, xpack);
    gemm_kernel<<<dim3(512, KSPLIT), 256, 0, stream>>>(weight_fp4, wscale, ws2, xpack, out);
}